// Round 5
// baseline (324.337 us; speedup 1.0000x reference)
//
#include <hip/hip_runtime.h>

// BrickVectorEdgeModel on MI355X (gfx950).
// R12: edge occupancy attack. R10 (less VALU) and R11 (deeper W prefetch)
// were both NULL on edge dur -> limiter is latency, not VALU count or W
// issue depth: 1 block/CU (159KB LDS) = 2 waves/SIMD, Occupancy 22%, and
// each ds_read->4xMFMA chain covers ~19cyc vs ~64+cyc LDS latency, with
// barrier-exposed phases idling the matrix pipe. Fix: edge tile 144->64
// rows (1 i x 64 j), LDS 70.7KB -> 2 blocks/CU, 4 waves/SIMD; resident
// blocks mutually hide barriers/epilogues. 2304 blocks. W bytes/block
// unchanged (2.25GB L2-side total, ~6% of L2 ceiling at target dur).
// Node/prep: reverted to R7's proven prep+tiled-W 3-kernel path (R11's
// fp32-direct W was +13us: 2x bytes at 16-req/instr rate), keeping the
// packed cvt_pk epilogues (RNE-identical, VALUBusy 40->31 confirmed).
// Tiled W layout (per 512-col weight, elems): off(c,k) =
//   ((c>>4)*16 + (k>>5))*512 + (c&15)*32 + (k&31)

typedef short  short8  __attribute__((ext_vector_type(8)));
typedef short  short4v __attribute__((ext_vector_type(4)));
typedef float  f32x4   __attribute__((ext_vector_type(4)));

#define LDSW 520   // LDS row stride in bf16 elems (520*2B = 1040B, 16B-aligned)

__device__ inline unsigned short f2bf(float x) {
  unsigned u = __float_as_uint(x);
  unsigned r = (u + 0x7FFFu + ((u >> 16) & 1u)) >> 16;  // RNE
  return (unsigned short)r;
}

// v_cvt_pk_bf16_f32: D[15:0]=bf16(S0) RNE, D[31:16]=bf16(S1).
__device__ inline unsigned cvt_pk_bf16(float lo, float hi) {
  unsigned d;
  asm("v_cvt_pk_bf16_f32 %0, %1, %2" : "=v"(d) : "v"(lo), "v"(hi));
  return d;
}
// relu+pack 4 floats -> 2 dwords of bf16
__device__ inline uint2 relu_pack4(float x0, float x1, float x2, float x3) {
  uint2 s;
  s.x = cvt_pk_bf16(fmaxf(x0, 0.f), fmaxf(x1, 0.f));
  s.y = cvt_pk_bf16(fmaxf(x2, 0.f), fmaxf(x3, 0.f));
  return s;
}

__device__ __host__ inline int wtile_off(int c, int k) {
  return ((c >> 4) * 16 + (k >> 5)) * 512 + (c & 15) * 32 + (k & 31);
}

template <int MT, int NT>
__device__ inline void zero_acc(f32x4 (&acc)[MT][NT]) {
#pragma unroll
  for (int mt = 0; mt < MT; ++mt)
#pragma unroll
    for (int nt = 0; nt < NT; ++nt) {
      f32x4 z = {0.f, 0.f, 0.f, 0.f};
      acc[mt][nt] = z;
    }
}

// acc[mt][nt] (+)= W-tile x E-tile.  W as MFMA A-operand (m = out-col),
// E as B-operand (n = edge-row).  Lane holds 4 consecutive out-cols
// (kg*4+r) at edge-row (mt*16 + (lane&15)).
// W is in tiled layout: per (col_tile ct, ks) a contiguous 1KB fragment;
// lane's slice at (lane&15)*32 + (lane>>4)*8.  One wF load = coalesced 1KB.
// wF register double-buffered across ks; eF JIT from LDS, rotating 1-deep.
template <int MT, int NT>
__device__ inline void gemm_kloop(const short* E, const short* __restrict__ W,
                                  int lane, int nbase, f32x4 (&acc)[MT][NT]) {
  const int mrow = lane & 15, kg = lane >> 4;
  const short* El = E + mrow * LDSW + kg * 8;
  const short* Wl = W + (nbase >> 4) * 8192 + mrow * 32 + kg * 8;
  short8 wF[2][NT];
#pragma unroll
  for (int nt = 0; nt < NT; ++nt) wF[0][nt] = *(const short8*)(Wl + nt * 8192);
#pragma unroll
  for (int ks = 0; ks < 16; ++ks) {
    const int cur = ks & 1, nxt = cur ^ 1;
    if (ks < 15) {
      const int k1 = (ks + 1) * 512;
#pragma unroll
      for (int nt = 0; nt < NT; ++nt)
        wF[nxt][nt] = *(const short8*)(Wl + nt * 8192 + k1);
    }
    const int k0 = ks * 32;
    short8 e0 = *(const short8*)(El + k0);
#pragma unroll
    for (int mt = 0; mt < MT; ++mt) {
      const short8 ecur = e0;
      if (mt < MT - 1) e0 = *(const short8*)(El + (mt + 1) * 16 * LDSW + k0);
#pragma unroll
      for (int nt = 0; nt < NT; ++nt)
        acc[mt][nt] = __builtin_amdgcn_mfma_f32_16x16x32_bf16(
            wF[cur][nt], ecur, acc[mt][nt], 0, 0, 0);
    }
  }
}

// relu(acc + bias[outcol]) -> bf16 -> LDS, 8B vector writes. Packed convert.
template <int MT, int NT>
__device__ inline void store_relu_lds(short* E, const float* __restrict__ bias,
                                      int lane, int nbase, f32x4 (&acc)[MT][NT]) {
  const int mrow = lane & 15, kg = lane >> 4;
#pragma unroll
  for (int nt = 0; nt < NT; ++nt) {
    const int oc = nbase + nt * 16 + kg * 4;
    const float4 bs = *(const float4*)(bias + oc);
#pragma unroll
    for (int mt = 0; mt < MT; ++mt) {
      uint2 s = relu_pack4(acc[mt][nt][0] + bs.x, acc[mt][nt][1] + bs.y,
                           acc[mt][nt][2] + bs.z, acc[mt][nt][3] + bs.w);
      *(uint2*)&E[(mt * 16 + mrow) * LDSW + oc] = s;
    }
  }
}

// ---------------- prep: fp32 -> bf16 + tiled relayout ----------------
__global__ void prep_kernel(const float* __restrict__ Wa, const float* __restrict__ Wb,
                            const float* __restrict__ Wca, const float* __restrict__ Wcb,
                            const float* __restrict__ Wcc, const float* __restrict__ Wout,
                            short* __restrict__ outS) {
  const int tid = blockIdx.x * blockDim.x + threadIdx.x;
  const int stride = gridDim.x * blockDim.x;
  const int M = 262144;
  for (int i = tid; i < 6 * M + 1024; i += stride) {
    float x;
    int dst;
    if (i < M) {                       // WaB tiled
      const int c = i >> 9, k = i & 511;
      x = Wa[i];
      dst = wtile_off(c, k);
    } else if (i < 2 * M) {            // WbB tiled
      const int t = i - M, c = t >> 9, k = t & 511;
      x = Wb[t];
      dst = M + wtile_off(c, k);
    } else if (i < 3 * M) {            // Wuv: u-half, tiled cols 0..511
      const int t = i - 2 * M, c = t >> 9, k = t & 511;
      x = Wca[c * 1024 + k];
      dst = 2 * M + wtile_off(c, k);
    } else if (i < 4 * M) {            // Wuv: v-half, tiled cols 512..1023
      const int t = i - 3 * M, c = t >> 9, k = t & 511;
      x = Wca[c * 1024 + 512 + k];
      dst = 2 * M + wtile_off(512 + c, k);
    } else if (i < 5 * M) {            // WcbB tiled
      const int t = i - 4 * M, c = t >> 9, k = t & 511;
      x = Wcb[t];
      dst = 4 * M + wtile_off(c, k);
    } else if (i < 6 * M) {            // WccB tiled
      const int t = i - 5 * M, c = t >> 9, k = t & 511;
      x = Wcc[t];
      dst = 5 * M + wtile_off(c, k);
    } else {                           // Wout plain row-major
      x = Wout[i - 6 * M];
      dst = i;
    }
    outS[dst] = (short)f2bf(x);
  }
}

// ---------------- node stage: 3 per-layer tiled kernels (64 rows x 64 cols) ---
// MODE 1: X=bv fp32, out = relu(X@Wa^T + xy-term + ba + bxy) -> bf16
// MODE 2: X=f1 bf16, out = relu(X@Wb^T + bb) -> bf16
// MODE 3: X=f2 bf16, out = X@Wuv^T (1024 cols) -> fp32 u (cols<512) / v (>=512)
template <int MODE>
__global__ __launch_bounds__(256, 4) void node_layer(
    const void* __restrict__ Xin, const short* __restrict__ W,
    const float* __restrict__ bias, const float* __restrict__ xy,
    const float* __restrict__ Wxy, const float* __restrict__ bxy,
    void* __restrict__ Yout, float* __restrict__ vout, int colTiles) {
  __shared__ short X[64 * LDSW];
  __shared__ float xyl[128];
  const int tid = threadIdx.x, lane = tid & 63, wave = tid >> 6;
  const int rt = blockIdx.x / colTiles, ct = blockIdx.x % colTiles;
  const int row0 = rt * 64, c0 = ct * 64;

  if (MODE == 1) {
    const float* bv = (const float*)Xin;
    const int hc = (tid & 127) * 4, m0 = tid >> 7;
    for (int m = m0; m < 64; m += 2) {
      const float4 t = *(const float4*)(bv + (row0 + m) * 512 + hc);
      uint2 s;
      s.x = cvt_pk_bf16(t.x, t.y);
      s.y = cvt_pk_bf16(t.z, t.w);
      *(uint2*)&X[m * LDSW + hc] = s;
    }
    if (tid < 128) xyl[tid] = xy[row0 * 2 + tid];
  } else {
    const short* xb = (const short*)Xin;
    const int hc = (tid & 63) * 8, m0 = tid >> 6;
    for (int m = m0; m < 64; m += 4)
      *(short8*)&X[m * LDSW + hc] = *(const short8*)(xb + (row0 + m) * 512 + hc);
  }
  __syncthreads();

  const int nbase = c0 + wave * 16;
  f32x4 acc[4][1];
  zero_acc<4, 1>(acc);
  gemm_kloop<4, 1>(X, W, lane, nbase, acc);

  const int mrow = lane & 15, kg = lane >> 4;
  const int oc = nbase + kg * 4;
  if (MODE == 3) {
    float* u = (float*)Yout;
#pragma unroll
    for (int mt = 0; mt < 4; ++mt) {
      const int row = row0 + mt * 16 + mrow;
      if (oc < 512) *(f32x4*)&u[row * 512 + oc] = acc[mt][0];     // block-uniform branch
      else          *(f32x4*)&vout[row * 512 + oc - 512] = acc[mt][0];
    }
  } else {
    short* Y = (short*)Yout;
    const float4 bs = *(const float4*)(bias + oc);
    float b2[4] = {0.f, 0.f, 0.f, 0.f}, w0[4], w1[4];
    if (MODE == 1) {
      const float4 t = *(const float4*)(bxy + oc);
      b2[0] = t.x; b2[1] = t.y; b2[2] = t.z; b2[3] = t.w;
#pragma unroll
      for (int r = 0; r < 4; ++r) { w0[r] = Wxy[(oc + r) * 2]; w1[r] = Wxy[(oc + r) * 2 + 1]; }
    }
#pragma unroll
    for (int mt = 0; mt < 4; ++mt) {
      const int row = mt * 16 + mrow;
      float xv[4];
#pragma unroll
      for (int r = 0; r < 4; ++r) {
        xv[r] = acc[mt][0][r] + ((const float*)&bs)[r];
        if (MODE == 1) xv[r] += b2[r] + xyl[row * 2] * w0[r] + xyl[row * 2 + 1] * w1[r];
      }
      uint2 s = relu_pack4(xv[0], xv[1], xv[2], xv[3]);
      *(uint2*)&Y[(row0 + row) * 512 + oc] = s;
    }
  }
}

// ---------------- edge stage: fused E0 -> E1 -> E2 -> out ----------------
// 64-row tiles (1 i x 64 j): LDS 70,656 B -> 2 blocks/CU, 4 waves/SIMD.
// 2304 blocks = 9 rounds of 256 CUs. Resident blocks mutually hide each
// other's barriers / epilogues / W-load stalls.
__global__ __launch_bounds__(512, 4) void edge_kernel(
    const float* __restrict__ u, const float* __restrict__ v,
    const short* __restrict__ Wcb, const short* __restrict__ Wcc,
    const short* __restrict__ Wout,
    const float* __restrict__ bca, const float* __restrict__ bcb,
    const float* __restrict__ bcc, const float* __restrict__ bout,
    float* __restrict__ out) {
  __shared__ short A[64 * LDSW];       // 66,560 B
  __shared__ float red[64 * 2 * 8];    //  4,096 B
  const int tid = threadIdx.x, lane = tid & 63, wave = tid >> 6;
  const int blk = blockIdx.x;
  const int b = blk / 576, rem = blk % 576, i = rem / 3, jt = rem % 3;
  const float* urow0 = u + (b * 192 + jt * 64) * 512;  // row m: j = jt*64 + m
  const float* vrow  = v + (b * 192 + i) * 512;        // single i-row

  {  // Phase 0: E0 = relu(u[j] + v[i] + b_ca) -> bf16 LDS.  (v+b_ca) hoisted,
     // convert packed (v_cvt_pk_bf16_f32).
    const int hc = (tid & 127) * 4, m0 = tid >> 7;
    const float4 bb = *(const float4*)(bca + hc);
    const float4 a0 = *(const float4*)(vrow + hc);
    float4 vb;
    vb.x = a0.x + bb.x; vb.y = a0.y + bb.y; vb.z = a0.z + bb.z; vb.w = a0.w + bb.w;
#pragma unroll 4
    for (int m = m0; m < 64; m += 4) {
      const float4 uu = *(const float4*)(urow0 + m * 512 + hc);
      uint2 s = relu_pack4(uu.x + vb.x, uu.y + vb.y, uu.z + vb.z, uu.w + vb.w);
      *(uint2*)&A[m * LDSW + hc] = s;
    }
  }
  __syncthreads();

  const int nbase = wave * 64;
  f32x4 acc[4][4];

  // layer cb
  zero_acc<4, 4>(acc);
  gemm_kloop<4, 4>(A, Wcb, lane, nbase, acc);
  __syncthreads();                 // all waves done reading E0
  store_relu_lds<4, 4>(A, bcb, lane, nbase, acc);
  __syncthreads();

  // layer cc
  zero_acc<4, 4>(acc);
  gemm_kloop<4, 4>(A, Wcc, lane, nbase, acc);
  __syncthreads();
  store_relu_lds<4, 4>(A, bcc, lane, nbase, acc);
  __syncthreads();

  // final: out = E2 @ Wout^T + bout.  k-split across 8 waves, n padded 2->16.
  f32x4 oacc[4];
#pragma unroll
  for (int mt = 0; mt < 4; ++mt) { f32x4 z = {0.f, 0.f, 0.f, 0.f}; oacc[mt] = z; }
  const int n = lane & 15, kg2 = lane >> 4;
#pragma unroll
  for (int kk = 0; kk < 2; ++kk) {
    const int k0 = wave * 64 + kk * 32 + kg2 * 8;
    short8 bf = {0, 0, 0, 0, 0, 0, 0, 0};
    if (n < 2) bf = *(const short8*)(Wout + n * 512 + k0);
#pragma unroll
    for (int mt = 0; mt < 4; ++mt) {
      const short8 af = *(const short8*)(A + (mt * 16 + n) * LDSW + k0);
      oacc[mt] = __builtin_amdgcn_mfma_f32_16x16x32_bf16(af, bf, oacc[mt], 0, 0, 0);
    }
  }
  if (n < 2) {
#pragma unroll
    for (int mt = 0; mt < 4; ++mt)
#pragma unroll
      for (int r = 0; r < 4; ++r) {
        const int row = mt * 16 + kg2 * 4 + r;
        red[(row * 2 + n) * 8 + wave] = oacc[mt][r];
      }
  }
  __syncthreads();
  if (tid < 128) {
    const int row = tid >> 1, o = tid & 1;
    float s = bout[o];
#pragma unroll
    for (int w = 0; w < 8; ++w) s += red[(row * 2 + o) * 8 + w];
    out[((b * 192 + i) * 192 + jt * 64 + row) * 2 + o] = s;
  }
}

extern "C" void kernel_launch(void* const* d_in, const int* in_sizes, int n_in,
                              void* d_out, int out_size, void* d_ws, size_t ws_size,
                              hipStream_t stream) {
  const float* bv   = (const float*)d_in[0];
  const float* xy   = (const float*)d_in[1];
  const float* Wxy  = (const float*)d_in[2];
  const float* bxy  = (const float*)d_in[3];
  const float* Wa   = (const float*)d_in[4];
  const float* ba   = (const float*)d_in[5];
  const float* Wb   = (const float*)d_in[6];
  const float* bb   = (const float*)d_in[7];
  const float* Wca  = (const float*)d_in[8];
  const float* bca  = (const float*)d_in[9];
  const float* Wcb  = (const float*)d_in[10];
  const float* bcb  = (const float*)d_in[11];
  const float* Wcc  = (const float*)d_in[12];
  const float* bcc  = (const float*)d_in[13];
  const float* Wout = (const float*)d_in[14];
  const float* bout = (const float*)d_in[15];
  float* out = (float*)d_out;

  // ws layout (bytes): [0, 3,147,776) bf16 weights (tiled layout);
  // f1 bf16 @3,147,776 (aliased by u fp32, f1 dead before L3 writes u);
  // f2 bf16 @4,720,640; v fp32 @5,507,072; end 7,079,936.
  short* S = (short*)d_ws;
  char* base = (char*)d_ws;
  short* WaB   = S;
  short* WbB   = S + 262144;
  short* WuvB  = S + 524288;    // tiled, 1024 cols: ct 0-31 = W1 (u), 32-63 = W2 (v)
  short* WcbB  = S + 1048576;
  short* WccB  = S + 1310720;
  short* WoutB = S + 1572864;
  short* f1 = (short*)(base + 3147776);
  float* u  = (float*)(base + 3147776);
  short* f2 = (short*)(base + 4720640);
  float* v  = (float*)(base + 5507072);

  prep_kernel<<<512, 256, 0, stream>>>(Wa, Wb, Wca, Wcb, Wcc, Wout, S);
  node_layer<1><<<96, 256, 0, stream>>>(bv, WaB, ba, xy, Wxy, bxy, f1, nullptr, 8);
  node_layer<2><<<96, 256, 0, stream>>>(f1, WbB, bb, nullptr, nullptr, nullptr, f2, nullptr, 8);
  node_layer<3><<<192, 256, 0, stream>>>(f2, WuvB, nullptr, nullptr, nullptr, nullptr, u, v, 16);
  edge_kernel<<<2304, 512, 0, stream>>>(u, v, WcbB, WccB, WoutB, bca, bcb, bcc, bout, out);
}

// Round 6
// 314.826 us; speedup vs baseline: 1.0302x; 1.0302x over previous
//
#include <hip/hip_runtime.h>

// BrickVectorEdgeModel on MI355X (gfx950).
// R13: R12 retry with the spill fixed. R12's __launch_bounds__(512,4) was
// interpreted as 4 workgroups/CU (=8 waves/SIMD) -> VGPR cap 64 -> massive
// scratch spill (WRITE_SIZE 3.7MB->216MB, VGPR 128->64, edge 168->234us).
// The occupancy theory was never tested. This round: identical 64-row tile
// (1 i x 64 j, LDS 70.7KB, 2 blocks/CU, 4 waves/SIMD, 2304 blocks) with
// __launch_bounds__(512,2) (R7-proven: VGPR cap 128, no spill).
// Theory unchanged: edge is latency-bound (MfmaUtil+VALUBusy both mid, Occ
// 22% at 144-row tile); 2 resident blocks/CU mutually hide barriers,
// epilogues, and W-load stalls. W-stream at 64-row: 2.4GB aggregate from
// L2 (~58% of L2 ceiling at target dur) -- feasible.
// Node/prep: R7 structure + packed cvt_pk epilogues (VALUBusy 40->31).
// Tiled W layout (per 512-col weight, elems): off(c,k) =
//   ((c>>4)*16 + (k>>5))*512 + (c&15)*32 + (k&31)

typedef short  short8  __attribute__((ext_vector_type(8)));
typedef short  short4v __attribute__((ext_vector_type(4)));
typedef float  f32x4   __attribute__((ext_vector_type(4)));

#define LDSW 520   // LDS row stride in bf16 elems (520*2B = 1040B, 16B-aligned)

__device__ inline unsigned short f2bf(float x) {
  unsigned u = __float_as_uint(x);
  unsigned r = (u + 0x7FFFu + ((u >> 16) & 1u)) >> 16;  // RNE
  return (unsigned short)r;
}

// v_cvt_pk_bf16_f32: D[15:0]=bf16(S0) RNE, D[31:16]=bf16(S1).
__device__ inline unsigned cvt_pk_bf16(float lo, float hi) {
  unsigned d;
  asm("v_cvt_pk_bf16_f32 %0, %1, %2" : "=v"(d) : "v"(lo), "v"(hi));
  return d;
}
// relu+pack 4 floats -> 2 dwords of bf16
__device__ inline uint2 relu_pack4(float x0, float x1, float x2, float x3) {
  uint2 s;
  s.x = cvt_pk_bf16(fmaxf(x0, 0.f), fmaxf(x1, 0.f));
  s.y = cvt_pk_bf16(fmaxf(x2, 0.f), fmaxf(x3, 0.f));
  return s;
}

__device__ __host__ inline int wtile_off(int c, int k) {
  return ((c >> 4) * 16 + (k >> 5)) * 512 + (c & 15) * 32 + (k & 31);
}

template <int MT, int NT>
__device__ inline void zero_acc(f32x4 (&acc)[MT][NT]) {
#pragma unroll
  for (int mt = 0; mt < MT; ++mt)
#pragma unroll
    for (int nt = 0; nt < NT; ++nt) {
      f32x4 z = {0.f, 0.f, 0.f, 0.f};
      acc[mt][nt] = z;
    }
}

// acc[mt][nt] (+)= W-tile x E-tile.  W as MFMA A-operand (m = out-col),
// E as B-operand (n = edge-row).  Lane holds 4 consecutive out-cols
// (kg*4+r) at edge-row (mt*16 + (lane&15)).
// W is in tiled layout: per (col_tile ct, ks) a contiguous 1KB fragment;
// lane's slice at (lane&15)*32 + (lane>>4)*8.  One wF load = coalesced 1KB.
// wF register double-buffered across ks; eF JIT from LDS, rotating 1-deep.
template <int MT, int NT>
__device__ inline void gemm_kloop(const short* E, const short* __restrict__ W,
                                  int lane, int nbase, f32x4 (&acc)[MT][NT]) {
  const int mrow = lane & 15, kg = lane >> 4;
  const short* El = E + mrow * LDSW + kg * 8;
  const short* Wl = W + (nbase >> 4) * 8192 + mrow * 32 + kg * 8;
  short8 wF[2][NT];
#pragma unroll
  for (int nt = 0; nt < NT; ++nt) wF[0][nt] = *(const short8*)(Wl + nt * 8192);
#pragma unroll
  for (int ks = 0; ks < 16; ++ks) {
    const int cur = ks & 1, nxt = cur ^ 1;
    if (ks < 15) {
      const int k1 = (ks + 1) * 512;
#pragma unroll
      for (int nt = 0; nt < NT; ++nt)
        wF[nxt][nt] = *(const short8*)(Wl + nt * 8192 + k1);
    }
    const int k0 = ks * 32;
    short8 e0 = *(const short8*)(El + k0);
#pragma unroll
    for (int mt = 0; mt < MT; ++mt) {
      const short8 ecur = e0;
      if (mt < MT - 1) e0 = *(const short8*)(El + (mt + 1) * 16 * LDSW + k0);
#pragma unroll
      for (int nt = 0; nt < NT; ++nt)
        acc[mt][nt] = __builtin_amdgcn_mfma_f32_16x16x32_bf16(
            wF[cur][nt], ecur, acc[mt][nt], 0, 0, 0);
    }
  }
}

// relu(acc + bias[outcol]) -> bf16 -> LDS, 8B vector writes. Packed convert.
template <int MT, int NT>
__device__ inline void store_relu_lds(short* E, const float* __restrict__ bias,
                                      int lane, int nbase, f32x4 (&acc)[MT][NT]) {
  const int mrow = lane & 15, kg = lane >> 4;
#pragma unroll
  for (int nt = 0; nt < NT; ++nt) {
    const int oc = nbase + nt * 16 + kg * 4;
    const float4 bs = *(const float4*)(bias + oc);
#pragma unroll
    for (int mt = 0; mt < MT; ++mt) {
      uint2 s = relu_pack4(acc[mt][nt][0] + bs.x, acc[mt][nt][1] + bs.y,
                           acc[mt][nt][2] + bs.z, acc[mt][nt][3] + bs.w);
      *(uint2*)&E[(mt * 16 + mrow) * LDSW + oc] = s;
    }
  }
}

// ---------------- prep: fp32 -> bf16 + tiled relayout ----------------
__global__ void prep_kernel(const float* __restrict__ Wa, const float* __restrict__ Wb,
                            const float* __restrict__ Wca, const float* __restrict__ Wcb,
                            const float* __restrict__ Wcc, const float* __restrict__ Wout,
                            short* __restrict__ outS) {
  const int tid = blockIdx.x * blockDim.x + threadIdx.x;
  const int stride = gridDim.x * blockDim.x;
  const int M = 262144;
  for (int i = tid; i < 6 * M + 1024; i += stride) {
    float x;
    int dst;
    if (i < M) {                       // WaB tiled
      const int c = i >> 9, k = i & 511;
      x = Wa[i];
      dst = wtile_off(c, k);
    } else if (i < 2 * M) {            // WbB tiled
      const int t = i - M, c = t >> 9, k = t & 511;
      x = Wb[t];
      dst = M + wtile_off(c, k);
    } else if (i < 3 * M) {            // Wuv: u-half, tiled cols 0..511
      const int t = i - 2 * M, c = t >> 9, k = t & 511;
      x = Wca[c * 1024 + k];
      dst = 2 * M + wtile_off(c, k);
    } else if (i < 4 * M) {            // Wuv: v-half, tiled cols 512..1023
      const int t = i - 3 * M, c = t >> 9, k = t & 511;
      x = Wca[c * 1024 + 512 + k];
      dst = 2 * M + wtile_off(512 + c, k);
    } else if (i < 5 * M) {            // WcbB tiled
      const int t = i - 4 * M, c = t >> 9, k = t & 511;
      x = Wcb[t];
      dst = 4 * M + wtile_off(c, k);
    } else if (i < 6 * M) {            // WccB tiled
      const int t = i - 5 * M, c = t >> 9, k = t & 511;
      x = Wcc[t];
      dst = 5 * M + wtile_off(c, k);
    } else {                           // Wout plain row-major
      x = Wout[i - 6 * M];
      dst = i;
    }
    outS[dst] = (short)f2bf(x);
  }
}

// ---------------- node stage: 3 per-layer tiled kernels (64 rows x 64 cols) ---
// MODE 1: X=bv fp32, out = relu(X@Wa^T + xy-term + ba + bxy) -> bf16
// MODE 2: X=f1 bf16, out = relu(X@Wb^T + bb) -> bf16
// MODE 3: X=f2 bf16, out = X@Wuv^T (1024 cols) -> fp32 u (cols<512) / v (>=512)
template <int MODE>
__global__ __launch_bounds__(256, 4) void node_layer(
    const void* __restrict__ Xin, const short* __restrict__ W,
    const float* __restrict__ bias, const float* __restrict__ xy,
    const float* __restrict__ Wxy, const float* __restrict__ bxy,
    void* __restrict__ Yout, float* __restrict__ vout, int colTiles) {
  __shared__ short X[64 * LDSW];
  __shared__ float xyl[128];
  const int tid = threadIdx.x, lane = tid & 63, wave = tid >> 6;
  const int rt = blockIdx.x / colTiles, ct = blockIdx.x % colTiles;
  const int row0 = rt * 64, c0 = ct * 64;

  if (MODE == 1) {
    const float* bv = (const float*)Xin;
    const int hc = (tid & 127) * 4, m0 = tid >> 7;
    for (int m = m0; m < 64; m += 2) {
      const float4 t = *(const float4*)(bv + (row0 + m) * 512 + hc);
      uint2 s;
      s.x = cvt_pk_bf16(t.x, t.y);
      s.y = cvt_pk_bf16(t.z, t.w);
      *(uint2*)&X[m * LDSW + hc] = s;
    }
    if (tid < 128) xyl[tid] = xy[row0 * 2 + tid];
  } else {
    const short* xb = (const short*)Xin;
    const int hc = (tid & 63) * 8, m0 = tid >> 6;
    for (int m = m0; m < 64; m += 4)
      *(short8*)&X[m * LDSW + hc] = *(const short8*)(xb + (row0 + m) * 512 + hc);
  }
  __syncthreads();

  const int nbase = c0 + wave * 16;
  f32x4 acc[4][1];
  zero_acc<4, 1>(acc);
  gemm_kloop<4, 1>(X, W, lane, nbase, acc);

  const int mrow = lane & 15, kg = lane >> 4;
  const int oc = nbase + kg * 4;
  if (MODE == 3) {
    float* u = (float*)Yout;
#pragma unroll
    for (int mt = 0; mt < 4; ++mt) {
      const int row = row0 + mt * 16 + mrow;
      if (oc < 512) *(f32x4*)&u[row * 512 + oc] = acc[mt][0];     // block-uniform branch
      else          *(f32x4*)&vout[row * 512 + oc - 512] = acc[mt][0];
    }
  } else {
    short* Y = (short*)Yout;
    const float4 bs = *(const float4*)(bias + oc);
    float b2[4] = {0.f, 0.f, 0.f, 0.f}, w0[4], w1[4];
    if (MODE == 1) {
      const float4 t = *(const float4*)(bxy + oc);
      b2[0] = t.x; b2[1] = t.y; b2[2] = t.z; b2[3] = t.w;
#pragma unroll
      for (int r = 0; r < 4; ++r) { w0[r] = Wxy[(oc + r) * 2]; w1[r] = Wxy[(oc + r) * 2 + 1]; }
    }
#pragma unroll
    for (int mt = 0; mt < 4; ++mt) {
      const int row = mt * 16 + mrow;
      float xv[4];
#pragma unroll
      for (int r = 0; r < 4; ++r) {
        xv[r] = acc[mt][0][r] + ((const float*)&bs)[r];
        if (MODE == 1) xv[r] += b2[r] + xyl[row * 2] * w0[r] + xyl[row * 2 + 1] * w1[r];
      }
      uint2 s = relu_pack4(xv[0], xv[1], xv[2], xv[3]);
      *(uint2*)&Y[(row0 + row) * 512 + oc] = s;
    }
  }
}

// ---------------- edge stage: fused E0 -> E1 -> E2 -> out ----------------
// 64-row tiles (1 i x 64 j): LDS 70,656 B -> 2 blocks/CU, 4 waves/SIMD.
// 2304 blocks = 9 rounds of 256 CUs. Resident blocks mutually hide each
// other's barriers / epilogues / W-load stalls.
// __launch_bounds__(512,2): R7-proven VGPR cap 128 -- R12's (512,4) forced
// VGPR to 64 and spilled ~190B/thread (216MB scratch writes/dispatch).
__global__ __launch_bounds__(512, 2) void edge_kernel(
    const float* __restrict__ u, const float* __restrict__ v,
    const short* __restrict__ Wcb, const short* __restrict__ Wcc,
    const short* __restrict__ Wout,
    const float* __restrict__ bca, const float* __restrict__ bcb,
    const float* __restrict__ bcc, const float* __restrict__ bout,
    float* __restrict__ out) {
  __shared__ short A[64 * LDSW];       // 66,560 B
  __shared__ float red[64 * 2 * 8];    //  4,096 B
  const int tid = threadIdx.x, lane = tid & 63, wave = tid >> 6;
  const int blk = blockIdx.x;
  const int b = blk / 576, rem = blk % 576, i = rem / 3, jt = rem % 3;
  const float* urow0 = u + (b * 192 + jt * 64) * 512;  // row m: j = jt*64 + m
  const float* vrow  = v + (b * 192 + i) * 512;        // single i-row

  {  // Phase 0: E0 = relu(u[j] + v[i] + b_ca) -> bf16 LDS.  (v+b_ca) hoisted,
     // convert packed (v_cvt_pk_bf16_f32).
    const int hc = (tid & 127) * 4, m0 = tid >> 7;
    const float4 bb = *(const float4*)(bca + hc);
    const float4 a0 = *(const float4*)(vrow + hc);
    float4 vb;
    vb.x = a0.x + bb.x; vb.y = a0.y + bb.y; vb.z = a0.z + bb.z; vb.w = a0.w + bb.w;
#pragma unroll 4
    for (int m = m0; m < 64; m += 4) {
      const float4 uu = *(const float4*)(urow0 + m * 512 + hc);
      uint2 s = relu_pack4(uu.x + vb.x, uu.y + vb.y, uu.z + vb.z, uu.w + vb.w);
      *(uint2*)&A[m * LDSW + hc] = s;
    }
  }
  __syncthreads();

  const int nbase = wave * 64;
  f32x4 acc[4][4];

  // layer cb
  zero_acc<4, 4>(acc);
  gemm_kloop<4, 4>(A, Wcb, lane, nbase, acc);
  __syncthreads();                 // all waves done reading E0
  store_relu_lds<4, 4>(A, bcb, lane, nbase, acc);
  __syncthreads();

  // layer cc
  zero_acc<4, 4>(acc);
  gemm_kloop<4, 4>(A, Wcc, lane, nbase, acc);
  __syncthreads();
  store_relu_lds<4, 4>(A, bcc, lane, nbase, acc);
  __syncthreads();

  // final: out = E2 @ Wout^T + bout.  k-split across 8 waves, n padded 2->16.
  f32x4 oacc[4];
#pragma unroll
  for (int mt = 0; mt < 4; ++mt) { f32x4 z = {0.f, 0.f, 0.f, 0.f}; oacc[mt] = z; }
  const int n = lane & 15, kg2 = lane >> 4;
#pragma unroll
  for (int kk = 0; kk < 2; ++kk) {
    const int k0 = wave * 64 + kk * 32 + kg2 * 8;
    short8 bf = {0, 0, 0, 0, 0, 0, 0, 0};
    if (n < 2) bf = *(const short8*)(Wout + n * 512 + k0);
#pragma unroll
    for (int mt = 0; mt < 4; ++mt) {
      const short8 af = *(const short8*)(A + (mt * 16 + n) * LDSW + k0);
      oacc[mt] = __builtin_amdgcn_mfma_f32_16x16x32_bf16(af, bf, oacc[mt], 0, 0, 0);
    }
  }
  if (n < 2) {
#pragma unroll
    for (int mt = 0; mt < 4; ++mt)
#pragma unroll
      for (int r = 0; r < 4; ++r) {
        const int row = mt * 16 + kg2 * 4 + r;
        red[(row * 2 + n) * 8 + wave] = oacc[mt][r];
      }
  }
  __syncthreads();
  if (tid < 128) {
    const int row = tid >> 1, o = tid & 1;
    float s = bout[o];
#pragma unroll
    for (int w = 0; w < 8; ++w) s += red[(row * 2 + o) * 8 + w];
    out[((b * 192 + i) * 192 + jt * 64 + row) * 2 + o] = s;
  }
}

extern "C" void kernel_launch(void* const* d_in, const int* in_sizes, int n_in,
                              void* d_out, int out_size, void* d_ws, size_t ws_size,
                              hipStream_t stream) {
  const float* bv   = (const float*)d_in[0];
  const float* xy   = (const float*)d_in[1];
  const float* Wxy  = (const float*)d_in[2];
  const float* bxy  = (const float*)d_in[3];
  const float* Wa   = (const float*)d_in[4];
  const float* ba   = (const float*)d_in[5];
  const float* Wb   = (const float*)d_in[6];
  const float* bb   = (const float*)d_in[7];
  const float* Wca  = (const float*)d_in[8];
  const float* bca  = (const float*)d_in[9];
  const float* Wcb  = (const float*)d_in[10];
  const float* bcb  = (const float*)d_in[11];
  const float* Wcc  = (const float*)d_in[12];
  const float* bcc  = (const float*)d_in[13];
  const float* Wout = (const float*)d_in[14];
  const float* bout = (const float*)d_in[15];
  float* out = (float*)d_out;

  // ws layout (bytes): [0, 3,147,776) bf16 weights (tiled layout);
  // f1 bf16 @3,147,776 (aliased by u fp32, f1 dead before L3 writes u);
  // f2 bf16 @4,720,640; v fp32 @5,507,072; end 7,079,936.
  short* S = (short*)d_ws;
  char* base = (char*)d_ws;
  short* WaB   = S;
  short* WbB   = S + 262144;
  short* WuvB  = S + 524288;    // tiled, 1024 cols: ct 0-31 = W1 (u), 32-63 = W2 (v)
  short* WcbB  = S + 1048576;
  short* WccB  = S + 1310720;
  short* WoutB = S + 1572864;
  short* f1 = (short*)(base + 3147776);
  float* u  = (float*)(base + 3147776);
  short* f2 = (short*)(base + 4720640);
  float* v  = (float*)(base + 5507072);

  prep_kernel<<<512, 256, 0, stream>>>(Wa, Wb, Wca, Wcb, Wcc, Wout, S);
  node_layer<1><<<96, 256, 0, stream>>>(bv, WaB, ba, xy, Wxy, bxy, f1, nullptr, 8);
  node_layer<2><<<96, 256, 0, stream>>>(f1, WbB, bb, nullptr, nullptr, nullptr, f2, nullptr, 8);
  node_layer<3><<<192, 256, 0, stream>>>(f2, WuvB, nullptr, nullptr, nullptr, nullptr, u, v, 16);
  edge_kernel<<<2304, 512, 0, stream>>>(u, v, WcbB, WccB, WoutB, bca, bcb, bcc, bout, out);
}

// Round 7
// 250.689 us; speedup vs baseline: 1.2938x; 1.2558x over previous
//
#include <hip/hip_runtime.h>

// BrickVectorEdgeModel on MI355X (gfx950).
// R14: node-stage WIDENING + full edge revert.
// Model established R10-R13: edge = ~115us fixed + ~11us/MB-of-W-per-CU.
// 144-row tile (1024 blocks, 4/CU) minimizes W/CU under the LDS cap ->
// edge ~156us is near this structure's floor; R10's cvt_pk edge edit
// regressed it (156->168, 5-dispatch consistent) -> edge reverted R7-exact.
// Wall - edge ~= 100-107us across R0/R11/R13 = prep+node DURATIONS:
// 96/96/192-block grids leave 5/8 of 256 CUs idle, latency-bound.
// Fix: retile node layers 64x64 -> 16x64 (MT=1), grids 384/384/768,
// ~6 resident blocks/CU, W/block 64KB (aggregate 25MB L2 - trivial).
// R8's fusion failed from 24-block W-replication; this keeps stream-ordered
// launches (no fences) and just raises parallelism.
// Tiled W layout (per 512-col weight, elems): off(c,k) =
//   ((c>>4)*16 + (k>>5))*512 + (c&15)*32 + (k&31)

typedef short  short8  __attribute__((ext_vector_type(8)));
typedef short  short4v __attribute__((ext_vector_type(4)));
typedef float  f32x4   __attribute__((ext_vector_type(4)));

#define LDSW 520   // LDS row stride in bf16 elems (520*2B = 1040B, 16B-aligned)

__device__ inline unsigned short f2bf(float x) {
  unsigned u = __float_as_uint(x);
  unsigned r = (u + 0x7FFFu + ((u >> 16) & 1u)) >> 16;  // RNE
  return (unsigned short)r;
}

__device__ __host__ inline int wtile_off(int c, int k) {
  return ((c >> 4) * 16 + (k >> 5)) * 512 + (c & 15) * 32 + (k & 31);
}

template <int MT, int NT>
__device__ inline void zero_acc(f32x4 (&acc)[MT][NT]) {
#pragma unroll
  for (int mt = 0; mt < MT; ++mt)
#pragma unroll
    for (int nt = 0; nt < NT; ++nt) {
      f32x4 z = {0.f, 0.f, 0.f, 0.f};
      acc[mt][nt] = z;
    }
}

// acc[mt][nt] (+)= W-tile x E-tile.  W as MFMA A-operand (m = out-col),
// E as B-operand (n = edge-row).  Lane holds 4 consecutive out-cols
// (kg*4+r) at edge-row (mt*16 + (lane&15)).
// W is in tiled layout: per (col_tile ct, ks) a contiguous 1KB fragment;
// lane's slice at (lane&15)*32 + (lane>>4)*8.  One wF load = coalesced 1KB.
// wF register double-buffered across ks; eF JIT from LDS, rotating 1-deep.
template <int MT, int NT>
__device__ inline void gemm_kloop(const short* E, const short* __restrict__ W,
                                  int lane, int nbase, f32x4 (&acc)[MT][NT]) {
  const int mrow = lane & 15, kg = lane >> 4;
  const short* El = E + mrow * LDSW + kg * 8;
  const short* Wl = W + (nbase >> 4) * 8192 + mrow * 32 + kg * 8;
  short8 wF[2][NT];
#pragma unroll
  for (int nt = 0; nt < NT; ++nt) wF[0][nt] = *(const short8*)(Wl + nt * 8192);
#pragma unroll
  for (int ks = 0; ks < 16; ++ks) {
    const int cur = ks & 1, nxt = cur ^ 1;
    if (ks < 15) {
      const int k1 = (ks + 1) * 512;
#pragma unroll
      for (int nt = 0; nt < NT; ++nt)
        wF[nxt][nt] = *(const short8*)(Wl + nt * 8192 + k1);
    }
    const int k0 = ks * 32;
    short8 e0 = *(const short8*)(El + k0);
#pragma unroll
    for (int mt = 0; mt < MT; ++mt) {
      const short8 ecur = e0;
      if (mt < MT - 1) e0 = *(const short8*)(El + (mt + 1) * 16 * LDSW + k0);
#pragma unroll
      for (int nt = 0; nt < NT; ++nt)
        acc[mt][nt] = __builtin_amdgcn_mfma_f32_16x16x32_bf16(
            wF[cur][nt], ecur, acc[mt][nt], 0, 0, 0);
    }
  }
}

// relu(acc + bias[outcol]) -> bf16 -> LDS, 8B vector writes.
template <int MT, int NT>
__device__ inline void store_relu_lds(short* E, const float* __restrict__ bias,
                                      int lane, int nbase, f32x4 (&acc)[MT][NT]) {
  const int mrow = lane & 15, kg = lane >> 4;
#pragma unroll
  for (int nt = 0; nt < NT; ++nt) {
    const int oc = nbase + nt * 16 + kg * 4;
    const float4 bs = *(const float4*)(bias + oc);
#pragma unroll
    for (int mt = 0; mt < MT; ++mt) {
      short4v s;
      s.x = (short)f2bf(fmaxf(acc[mt][nt][0] + bs.x, 0.f));
      s.y = (short)f2bf(fmaxf(acc[mt][nt][1] + bs.y, 0.f));
      s.z = (short)f2bf(fmaxf(acc[mt][nt][2] + bs.z, 0.f));
      s.w = (short)f2bf(fmaxf(acc[mt][nt][3] + bs.w, 0.f));
      *(short4v*)&E[(mt * 16 + mrow) * LDSW + oc] = s;
    }
  }
}

// ---------------- prep: fp32 -> bf16 + tiled relayout ----------------
__global__ void prep_kernel(const float* __restrict__ Wa, const float* __restrict__ Wb,
                            const float* __restrict__ Wca, const float* __restrict__ Wcb,
                            const float* __restrict__ Wcc, const float* __restrict__ Wout,
                            short* __restrict__ outS) {
  const int tid = blockIdx.x * blockDim.x + threadIdx.x;
  const int stride = gridDim.x * blockDim.x;
  const int M = 262144;
  for (int i = tid; i < 6 * M + 1024; i += stride) {
    float x;
    int dst;
    if (i < M) {                       // WaB tiled
      const int c = i >> 9, k = i & 511;
      x = Wa[i];
      dst = wtile_off(c, k);
    } else if (i < 2 * M) {            // WbB tiled
      const int t = i - M, c = t >> 9, k = t & 511;
      x = Wb[t];
      dst = M + wtile_off(c, k);
    } else if (i < 3 * M) {            // Wuv: u-half, tiled cols 0..511
      const int t = i - 2 * M, c = t >> 9, k = t & 511;
      x = Wca[c * 1024 + k];
      dst = 2 * M + wtile_off(c, k);
    } else if (i < 4 * M) {            // Wuv: v-half, tiled cols 512..1023
      const int t = i - 3 * M, c = t >> 9, k = t & 511;
      x = Wca[c * 1024 + 512 + k];
      dst = 2 * M + wtile_off(512 + c, k);
    } else if (i < 5 * M) {            // WcbB tiled
      const int t = i - 4 * M, c = t >> 9, k = t & 511;
      x = Wcb[t];
      dst = 4 * M + wtile_off(c, k);
    } else if (i < 6 * M) {            // WccB tiled
      const int t = i - 5 * M, c = t >> 9, k = t & 511;
      x = Wcc[t];
      dst = 5 * M + wtile_off(c, k);
    } else {                           // Wout plain row-major
      x = Wout[i - 6 * M];
      dst = i;
    }
    outS[dst] = (short)f2bf(x);
  }
}

// ---------------- node stage: 3 per-layer tiled kernels (16 rows x 64 cols) --
// MODE 1: X=bv fp32, out = relu(X@Wa^T + xy-term + ba + bxy) -> bf16
// MODE 2: X=f1 bf16, out = relu(X@Wb^T + bb) -> bf16
// MODE 3: X=f2 bf16, out = X@Wuv^T (1024 cols) -> fp32 u (cols<512) / v (>=512)
// 16-row tiles: LDS 16.6KB, ~6 resident blocks/CU; grids 384/384/768 fill
// all 256 CUs (R7's 64-row tiles ran 96/96/192 blocks = 5/8 of GPU idle).
template <int MODE>
__global__ __launch_bounds__(256, 4) void node_layer(
    const void* __restrict__ Xin, const short* __restrict__ W,
    const float* __restrict__ bias, const float* __restrict__ xy,
    const float* __restrict__ Wxy, const float* __restrict__ bxy,
    void* __restrict__ Yout, float* __restrict__ vout, int colTiles) {
  __shared__ short X[16 * LDSW];
  __shared__ float xyl[32];
  const int tid = threadIdx.x, lane = tid & 63, wave = tid >> 6;
  const int rt = blockIdx.x / colTiles, ct = blockIdx.x % colTiles;
  const int row0 = rt * 16, c0 = ct * 64;

  if (MODE == 1) {
    const float* bv = (const float*)Xin;
    const int hc = (tid & 127) * 4, m0 = tid >> 7;
    for (int m = m0; m < 16; m += 2) {
      const float4 t = *(const float4*)(bv + (row0 + m) * 512 + hc);
      short4v s;
      s.x = (short)f2bf(t.x); s.y = (short)f2bf(t.y);
      s.z = (short)f2bf(t.z); s.w = (short)f2bf(t.w);
      *(short4v*)&X[m * LDSW + hc] = s;
    }
    if (tid < 32) xyl[tid] = xy[row0 * 2 + tid];
  } else {
    const short* xb = (const short*)Xin;
    const int hc = (tid & 63) * 8, m0 = tid >> 6;
    for (int m = m0; m < 16; m += 4)
      *(short8*)&X[m * LDSW + hc] = *(const short8*)(xb + (row0 + m) * 512 + hc);
  }
  __syncthreads();

  const int nbase = c0 + wave * 16;
  f32x4 acc[1][1];
  zero_acc<1, 1>(acc);
  gemm_kloop<1, 1>(X, W, lane, nbase, acc);

  const int mrow = lane & 15, kg = lane >> 4;
  const int oc = nbase + kg * 4;
  if (MODE == 3) {
    float* u = (float*)Yout;
    const int row = row0 + mrow;
    if (oc < 512) *(f32x4*)&u[row * 512 + oc] = acc[0][0];     // block-uniform branch
    else          *(f32x4*)&vout[row * 512 + oc - 512] = acc[0][0];
  } else {
    short* Y = (short*)Yout;
    const float4 bs = *(const float4*)(bias + oc);
    float b2[4] = {0.f, 0.f, 0.f, 0.f}, w0[4], w1[4];
    if (MODE == 1) {
      const float4 t = *(const float4*)(bxy + oc);
      b2[0] = t.x; b2[1] = t.y; b2[2] = t.z; b2[3] = t.w;
#pragma unroll
      for (int r = 0; r < 4; ++r) { w0[r] = Wxy[(oc + r) * 2]; w1[r] = Wxy[(oc + r) * 2 + 1]; }
    }
    const int row = mrow;
    short4v s;
#pragma unroll
    for (int r = 0; r < 4; ++r) {
      float xv = acc[0][0][r] + ((const float*)&bs)[r];
      if (MODE == 1) xv += b2[r] + xyl[row * 2] * w0[r] + xyl[row * 2 + 1] * w1[r];
      ((short*)&s)[r] = (short)f2bf(fmaxf(xv, 0.f));
    }
    *(short4v*)&Y[(row0 + row) * 512 + oc] = s;
  }
}

// ---------------- edge stage: fused E0 -> E1 -> E2 -> out ----------------
// R7-EXACT. 144-row tiles (3 i x 48 j): LDS 158,976 B -> 1 block/CU, 8 waves.
// 1024 blocks = exactly 4 full rounds of 256 CUs. W/CU = 4.2 MB (the minimum
// under the LDS cap; model: edge = ~115us fixed + ~11us/MB-W-per-CU).
__global__ __launch_bounds__(512, 2) void edge_kernel(
    const float* __restrict__ u, const float* __restrict__ v,
    const short* __restrict__ Wcb, const short* __restrict__ Wcc,
    const short* __restrict__ Wout,
    const float* __restrict__ bca, const float* __restrict__ bcb,
    const float* __restrict__ bcc, const float* __restrict__ bout,
    float* __restrict__ out) {
  __shared__ short A[144 * LDSW];      // 149,760 B
  __shared__ float red[144 * 2 * 8];   //   9,216 B
  const int tid = threadIdx.x, lane = tid & 63, wave = tid >> 6;
  const int blk = blockIdx.x;
  const int b = blk >> 8, rem = blk & 255, ip = rem >> 2, jt = rem & 3;
  const float* urow0 = u + (b * 192 + jt * 48) * 512;        // row m: j = jt*48 + m%48
  const float* vrow0 = v + (b * 192 + ip * 3) * 512;         // row m: i = ip*3 + m/48

  {  // Phase 0: E0 = relu(u[j] + v[i] + b_ca) -> bf16 LDS
    const int hc = (tid & 127) * 4, m0 = tid >> 7;
    const float4 v0 = *(const float4*)(vrow0 + hc);
    const float4 v1 = *(const float4*)(vrow0 + 512 + hc);
    const float4 v2 = *(const float4*)(vrow0 + 1024 + hc);
    const float4 bb = *(const float4*)(bca + hc);
#pragma unroll 4
    for (int m = m0; m < 144; m += 4) {
      const int ii = (m >= 96) ? 2 : (m >= 48 ? 1 : 0);
      const int jj = m - ii * 48;
      const float4 vv = (ii == 0) ? v0 : (ii == 1) ? v1 : v2;
      const float4 uu = *(const float4*)(urow0 + jj * 512 + hc);
      short4v s;
      s.x = (short)f2bf(fmaxf(uu.x + vv.x + bb.x, 0.f));
      s.y = (short)f2bf(fmaxf(uu.y + vv.y + bb.y, 0.f));
      s.z = (short)f2bf(fmaxf(uu.z + vv.z + bb.z, 0.f));
      s.w = (short)f2bf(fmaxf(uu.w + vv.w + bb.w, 0.f));
      *(short4v*)&A[m * LDSW + hc] = s;
    }
  }
  __syncthreads();

  const int nbase = wave * 64;
  f32x4 acc[9][4];

  // layer cb
  zero_acc<9, 4>(acc);
  gemm_kloop<9, 4>(A, Wcb, lane, nbase, acc);
  __syncthreads();                 // all waves done reading E0
  store_relu_lds<9, 4>(A, bcb, lane, nbase, acc);
  __syncthreads();

  // layer cc
  zero_acc<9, 4>(acc);
  gemm_kloop<9, 4>(A, Wcc, lane, nbase, acc);
  __syncthreads();
  store_relu_lds<9, 4>(A, bcc, lane, nbase, acc);
  __syncthreads();

  // final: out = E2 @ Wout^T + bout.  k-split across 8 waves, n padded 2->16.
  f32x4 oacc[9];
#pragma unroll
  for (int mt = 0; mt < 9; ++mt) { f32x4 z = {0.f, 0.f, 0.f, 0.f}; oacc[mt] = z; }
  const int n = lane & 15, kg2 = lane >> 4;
#pragma unroll
  for (int kk = 0; kk < 2; ++kk) {
    const int k0 = wave * 64 + kk * 32 + kg2 * 8;
    short8 bf = {0, 0, 0, 0, 0, 0, 0, 0};
    if (n < 2) bf = *(const short8*)(Wout + n * 512 + k0);
#pragma unroll
    for (int mt = 0; mt < 9; ++mt) {
      const short8 af = *(const short8*)(A + (mt * 16 + n) * LDSW + k0);
      oacc[mt] = __builtin_amdgcn_mfma_f32_16x16x32_bf16(af, bf, oacc[mt], 0, 0, 0);
    }
  }
  if (n < 2) {
#pragma unroll
    for (int mt = 0; mt < 9; ++mt)
#pragma unroll
      for (int r = 0; r < 4; ++r) {
        const int row = mt * 16 + kg2 * 4 + r;
        red[(row * 2 + n) * 8 + wave] = oacc[mt][r];
      }
  }
  __syncthreads();
  if (tid < 288) {
    const int row = tid >> 1, o = tid & 1;
    float s = bout[o];
#pragma unroll
    for (int w = 0; w < 8; ++w) s += red[(row * 2 + o) * 8 + w];
    const int ii = (row >= 96) ? 2 : (row >= 48 ? 1 : 0);
    const int jj = row - ii * 48;
    out[((b * 192 + ip * 3 + ii) * 192 + jt * 48 + jj) * 2 + o] = s;
  }
}

extern "C" void kernel_launch(void* const* d_in, const int* in_sizes, int n_in,
                              void* d_out, int out_size, void* d_ws, size_t ws_size,
                              hipStream_t stream) {
  const float* bv   = (const float*)d_in[0];
  const float* xy   = (const float*)d_in[1];
  const float* Wxy  = (const float*)d_in[2];
  const float* bxy  = (const float*)d_in[3];
  const float* Wa   = (const float*)d_in[4];
  const float* ba   = (const float*)d_in[5];
  const float* Wb   = (const float*)d_in[6];
  const float* bb   = (const float*)d_in[7];
  const float* Wca  = (const float*)d_in[8];
  const float* bca  = (const float*)d_in[9];
  const float* Wcb  = (const float*)d_in[10];
  const float* bcb  = (const float*)d_in[11];
  const float* Wcc  = (const float*)d_in[12];
  const float* bcc  = (const float*)d_in[13];
  const float* Wout = (const float*)d_in[14];
  const float* bout = (const float*)d_in[15];
  float* out = (float*)d_out;

  // ws layout (bytes): [0, 3,147,776) bf16 weights (tiled layout);
  // f1 bf16 @3,147,776 (aliased by u fp32, f1 dead before L3 writes u);
  // f2 bf16 @4,720,640; v fp32 @5,507,072; end 7,079,936.
  short* S = (short*)d_ws;
  char* base = (char*)d_ws;
  short* WaB   = S;
  short* WbB   = S + 262144;
  short* WuvB  = S + 524288;    // tiled, 1024 cols: ct 0-31 = W1 (u), 32-63 = W2 (v)
  short* WcbB  = S + 1048576;
  short* WccB  = S + 1310720;
  short* WoutB = S + 1572864;
  short* f1 = (short*)(base + 3147776);
  float* u  = (float*)(base + 3147776);
  short* f2 = (short*)(base + 4720640);
  float* v  = (float*)(base + 5507072);

  prep_kernel<<<512, 256, 0, stream>>>(Wa, Wb, Wca, Wcb, Wcc, Wout, S);
  node_layer<1><<<384, 256, 0, stream>>>(bv, WaB, ba, xy, Wxy, bxy, f1, nullptr, 8);
  node_layer<2><<<384, 256, 0, stream>>>(f1, WbB, bb, nullptr, nullptr, nullptr, f2, nullptr, 8);
  node_layer<3><<<768, 256, 0, stream>>>(f2, WuvB, nullptr, nullptr, nullptr, nullptr, u, v, 16);
  edge_kernel<<<1024, 512, 0, stream>>>(u, v, WcbB, WccB, WoutB, bca, bcb, bcc, bout, out);
}